// Round 3
// baseline (333.648 us; speedup 1.0000x reference)
//
#include <hip/hip_runtime.h>
#include <stdint.h>

#define B_ 64
#define T_ 4096
#define D_ 90
#define K_ 32
#define C_ 64   // number of T-chunks (chunk length = 64)

typedef float f32x16 __attribute__((ext_vector_type(16)));
typedef __bf16 bf16x8 __attribute__((ext_vector_type(8)));

// ---- workspace layout (float offsets). total ~8396928 floats = 33.6 MB ----
#define WS_A     0          // 1024 : softmax(transition) rows, A[j*32+k]
#define WS_PI    1024       // 32   : softmax(priors)
#define WS_C0    1056       // 32   : per-state emission constant
#define WS_MSUM  1088       // 64   : sum_t max_k em[b,t,k] (atomic)
#define WS_EACC  1152       // 4096 ints : per-(b,chunk) renorm exponent
#define WS_WF    5248       // 6144 bf16 : MFMA B-fragments of emission weights
#define WS_E     8320       // 8388608 bf16 : E^T[b][k][t] = exp(em - m_t)
#define WS_Q     4202624    // 4194304 : Q[b][c][k_new][j_old]

// block-swap involution: swap 4-7<->8-11 and 20-23<->24-27
__device__ __forceinline__ int perm_r(int r) {
  int t2 = (r >> 2) & 3;
  return r + ((t2 == 1) ? 4 : (t2 == 2) ? -4 : 0);
}
// pack two f32 -> bf16x2 dword (truncation; used in chunk recursion)
__device__ __forceinline__ uint32_t pk2(float hi, float lo) {
  return (__float_as_uint(hi) & 0xFFFF0000u) | (__float_as_uint(lo) >> 16);
}
// pack two f32 -> bf16x2 dword with round-to-nearest (emission path)
__device__ __forceinline__ uint32_t rnd_pk(float hi, float lo) {
  uint32_t uh = __float_as_uint(hi) + 0x8000u;
  uint32_t ul = __float_as_uint(lo) + 0x8000u;
  return (uh & 0xFFFF0000u) | (ul >> 16);
}
__device__ __forceinline__ float bf2f(ushort u) {
  return __uint_as_float(((uint32_t)u) << 16);
}
__device__ __forceinline__ bf16x8 mkbf(uint32_t a, uint32_t b, uint32_t c, uint32_t d) {
  union { uint32_t u[4]; bf16x8 v; } x;
  x.u[0] = a; x.u[1] = b; x.u[2] = c; x.u[3] = d;
  return x.v;
}

// ---------------- prep: softmaxes + emission weight fragments ----------------
__global__ __launch_bounds__(1024) void prep_kernel(
    const float* __restrict__ priors, const float* __restrict__ trans,
    const float* __restrict__ mu, const float* __restrict__ lv,
    float* __restrict__ ws) {
  int tid = threadIdx.x;
  {  // transition row softmax: tid = j*32+k, 32-lane groups are rows
    float v = trans[tid];
    float m = v;
    #pragma unroll
    for (int mk = 16; mk; mk >>= 1) m = fmaxf(m, __shfl_xor(m, mk));
    float e = expf(v - m);
    float s = e;
    #pragma unroll
    for (int mk = 16; mk; mk >>= 1) s += __shfl_xor(s, mk);
    ws[WS_A + tid] = e / s;
  }
  if (tid < 32) {  // prior softmax
    float v = priors[tid];
    float m = v;
    #pragma unroll
    for (int mk = 16; mk; mk >>= 1) m = fmaxf(m, __shfl_xor(m, mk));
    float e = expf(v - m);
    float s = e;
    #pragma unroll
    for (int mk = 16; mk; mk >>= 1) s += __shfl_xor(s, mk);
    ws[WS_PI + tid] = e / s;
  }
  // MFMA B-operand weight fragments, bf16, layout [c][mat][lane][j]
  // element = W[d = 16c + 8(lane>>5) + j][k = lane&31]; mat0 = -0.5*iv (x^2), mat1 = mu*iv (x)
  for (int i = tid; i < 6144; i += 1024) {
    int j = i & 7, l = (i >> 3) & 63, cm = i >> 9;
    int c = cm >> 1, mat = cm & 1;
    int h = l >> 5, nn = l & 31;
    int d = 16 * c + 8 * h + j;
    float v = 0.0f;
    if (d < D_) {
      float ivd = expf(-lv[nn * D_ + d]);
      v = (mat == 0) ? -0.5f * ivd : mu[nn * D_ + d] * ivd;
    }
    ((ushort*)(ws + WS_WF))[i] = (ushort)((__float_as_uint(v) + 0x8000u) >> 16);
  }
  if (tid < 32) {  // c0[k] = -0.5*(sum mu^2*iv + sum lv + D*log(2pi))
    float s = 0.0f;
    for (int d = 0; d < D_; ++d) {
      float l  = lv[tid * D_ + d];
      float iv = expf(-l);
      float m_ = mu[tid * D_ + d];
      s += m_ * m_ * iv + l;
    }
    ws[WS_C0 + tid] = -0.5f * (s + (float)D_ * 1.8378770664093453f);
  }
}

// ---------------- emission via MFMA: E^T[b][k][t] = exp(em - m_t) (bf16) ----------------
// LDS-staged X (coalesced float4), then per-wave 32-t tile, 12 mfma_32x32x16_bf16.
__global__ __launch_bounds__(256) void emis_kernel(const float* __restrict__ X,
                                                   float* __restrict__ ws) {
  __shared__ float xs[4 * 2888];     // 4 wave-regions of 32 rows x 90 (+8 pad)
  int tid = threadIdx.x;
  int l = tid & 63;
  int w = tid >> 6;
  int n = l & 31, h = l >> 5;
  int tB = blockIdx.x << 7;          // block covers 128 contiguous rows
  // stage: 2880 float4, fully coalesced; LDS regions padded per 32-row group
  const float4* Xg = (const float4*)(X + (size_t)tB * D_);
  #pragma unroll
  for (int it = 0; it < 12; ++it) {
    int i = tid + (it << 8);
    if (i < 2880) {
      int g = i / 720;               // 32-row group
      ((float4*)xs)[g * 722 + (i - g * 720)] = Xg[i];
    }
  }
  const uint4* wfp = (const uint4*)((const ushort*)(ws + WS_WF));
  uint4 wf[12];
  #pragma unroll
  for (int cm = 0; cm < 12; ++cm) wf[cm] = wfp[cm * 64 + l];   // coalesced b128
  float c0 = ws[WS_C0 + n];
  __syncthreads();
  int t0 = tB + (w << 5);
  int b  = t0 >> 12;
  const float* xrow = xs + w * 2888 + n * 90;       // A-row m = n
  f32x16 acc1, acc2;
  #pragma unroll
  for (int r = 0; r < 16; ++r) { acc1[r] = 0.0f; acc2[r] = 0.0f; }
  #pragma unroll
  for (int c = 0; c < 6; ++c) {
    float x[8];
    int s = 16 * c + 8 * h;                          // kk = d = s + j
    const float2* p = (const float2*)(xrow + s);     // 8B-aligned, 2-way bank alias (free)
    #pragma unroll
    for (int r = 0; r < 4; ++r) { float2 v = p[r]; x[2*r] = v.x; x[2*r+1] = v.y; }
    if (c == 5) {                                    // zero padded d >= 90
      #pragma unroll
      for (int j = 0; j < 8; ++j) if (s + j >= D_) x[j] = 0.0f;
    }
    union { uint32_t u[4]; bf16x8 v; } xb, x2b;
    #pragma unroll
    for (int r = 0; r < 4; ++r) {
      xb.u[r]  = rnd_pk(x[2*r+1], x[2*r]);
      x2b.u[r] = rnd_pk(x[2*r+1] * x[2*r+1], x[2*r] * x[2*r]);
    }
    union { uint4 u; bf16x8 v; } w2, w1;
    w2.u = wf[c * 2]; w1.u = wf[c * 2 + 1];
    acc1 = __builtin_amdgcn_mfma_f32_32x32x16_bf16(xb.v,  w1.v, acc1, 0, 0, 0);
    acc2 = __builtin_amdgcn_mfma_f32_32x32x16_bf16(x2b.v, w2.v, acc2, 0, 0, 0);
  }
  // C/D: col k = n, row t = (r&3) + 8*(r>>2) + 4*h
  float em[16], mrow[16];
  #pragma unroll
  for (int r = 0; r < 16; ++r) {
    float v = acc1[r] + acc2[r] + c0;
    em[r] = v;
    float m = v;
    #pragma unroll
    for (int mk = 1; mk <= 16; mk <<= 1) m = fmaxf(m, __shfl_xor(m, mk));  // max over k
    mrow[r] = m;
  }
  ushort* Ew = (ushort*)(ws + WS_E);
  size_t ebase = (size_t)(b * K_ + n) * T_ + (t0 & (T_ - 1));
  #pragma unroll
  for (int q = 0; q < 4; ++q) {  // regs 4q..4q+3 are consecutive t's: pack 4 bf16 -> 8B store
    float e0 = exp2f((em[4*q]   - mrow[4*q])   * 1.44269504088896f);
    float e1 = exp2f((em[4*q+1] - mrow[4*q+1]) * 1.44269504088896f);
    float e2 = exp2f((em[4*q+2] - mrow[4*q+2]) * 1.44269504088896f);
    float e3 = exp2f((em[4*q+3] - mrow[4*q+3]) * 1.44269504088896f);
    uint2 d;
    d.x = rnd_pk(e1, e0);
    d.y = rnd_pk(e3, e2);
    *(uint2*)(Ew + ebase + 8 * q + 4 * h) = d;
  }
  float msum = 0.0f;
  #pragma unroll
  for (int r = 0; r < 16; ++r) msum += mrow[r];
  msum += __shfl_xor(msum, 32);                      // both halves' 16 rows
  if (l == 0) atomicAdd(ws + WS_MSUM + b, msum);
}

// ---------------- phase 1: per-(b,chunk) transfer matrix via MFMA ----------------
// E loads vectorized: one uint4 (8 steps) per lane per group, prefetched a group ahead.
__global__ __launch_bounds__(64) void chunk_kernel(float* __restrict__ ws) {
  int l = threadIdx.x;
  int h = l >> 5, n = l & 31;
  int bc = blockIdx.x;
  int b = bc >> 6, c = bc & 63;
  int col = perm_r(n);                // logical output-state of this lane's A column
  const float* A = ws + WS_A;
  float astat[16];                    // A[s][col] for s = 8h+j and 16+8h+j
  #pragma unroll
  for (int j = 0; j < 8; ++j) {
    astat[j]     = A[(8 * h + j) * K_ + col];
    astat[8 + j] = A[(16 + 8 * h + j) * K_ + col];
  }
  uint32_t q[8];                      // Q fragments (bf16x2 dwords), init = I
  #pragma unroll
  for (int r = 0; r < 4; ++r) {
    int s0 = 8 * h + 2 * r;
    uint32_t lo = (s0 == n)     ? 0x3F80u : 0u;
    uint32_t hi = (s0 + 1 == n) ? 0x3F80u : 0u;
    q[r] = lo | (hi << 16);
    int s2 = s0 + 16;
    lo = (s2 == n)     ? 0x3F80u : 0u;
    hi = (s2 + 1 == n) ? 0x3F80u : 0u;
    q[4 + r] = lo | (hi << 16);
  }
  const ushort* Eb = (const ushort*)(ws + WS_E) + (size_t)(b * K_ + col) * T_ + c * 64;
  int eacc = 0;
  f32x16 acc;
  #pragma unroll
  for (int r = 0; r < 16; ++r) acc[r] = 0.0f;

  auto step = [&](float e0) {
    uint32_t au[8];
    #pragma unroll
    for (int r = 0; r < 4; ++r) {     // A-frag = astat * E[col], truncated to bf16
      au[r]     = pk2(astat[2 * r + 1] * e0, astat[2 * r] * e0);
      au[4 + r] = pk2(astat[8 + 2 * r + 1] * e0, astat[8 + 2 * r] * e0);
    }
    bf16x8 alo = mkbf(au[0], au[1], au[2], au[3]);
    bf16x8 ahi = mkbf(au[4], au[5], au[6], au[7]);
    bf16x8 qlo = mkbf(q[0], q[1], q[2], q[3]);
    bf16x8 qhi = mkbf(q[4], q[5], q[6], q[7]);
    f32x16 z;
    #pragma unroll
    for (int r = 0; r < 16; ++r) z[r] = 0.0f;
    acc = __builtin_amdgcn_mfma_f32_32x32x16_bf16(alo, qlo, z, 0, 0, 0);
    acc = __builtin_amdgcn_mfma_f32_32x32x16_bf16(ahi, qhi, acc, 0, 0, 0);
    #pragma unroll
    for (int r = 0; r < 4; ++r) {     // D regs -> next B-frag, in-lane repack only
      q[r]     = pk2(acc[2 * r + 1], acc[2 * r]);
      q[4 + r] = pk2(acc[8 + 2 * r + 1], acc[8 + 2 * r]);
    }
  };
  auto renorm = [&]() {               // exact power-of-2 renormalization
    float m = acc[0];
    #pragma unroll
    for (int r = 1; r < 16; ++r) m = fmaxf(m, acc[r]);
    #pragma unroll
    for (int mk = 1; mk <= 32; mk <<= 1) m = fmaxf(m, __shfl_xor(m, mk));
    int ex;
    frexpf(m, &ex);
    float sc = ldexpf(1.0f, -ex);
    eacc += ex;
    #pragma unroll
    for (int r = 0; r < 16; ++r) acc[r] *= sc;
    #pragma unroll
    for (int r = 0; r < 4; ++r) {     // re-pack q from renormalized acc
      q[r]     = pk2(acc[2 * r + 1], acc[2 * r]);
      q[4 + r] = pk2(acc[8 + 2 * r + 1], acc[8 + 2 * r]);
    }
  };

  uint4 ev = *(const uint4*)(Eb);     // group 0 (8 steps of E, 16B)
  int gstart = 0;
  if (c == 0) {                       // t=0 is the prior step: skip it
    uint4 evn = *(const uint4*)(Eb + 8);
    #pragma unroll
    for (int j = 1; j < 8; ++j) {
      uint32_t u = ((const uint32_t*)&ev)[j >> 1];
      step(bf2f((j & 1) ? (ushort)(u >> 16) : (ushort)(u & 0xFFFF)));
    }
    renorm();
    ev = evn;
    gstart = 1;
  }
  for (int g = gstart; g < 8; ++g) {
    uint4 evn;
    if (g < 7) evn = *(const uint4*)(Eb + 8 * (g + 1));   // prefetch next group
    #pragma unroll
    for (int j = 0; j < 8; ++j) {
      uint32_t u = ((const uint32_t*)&ev)[j >> 1];
      step(bf2f((j & 1) ? (ushort)(u >> 16) : (ushort)(u & 0xFFFF)));
    }
    renorm();
    ev = evn;
  }
  float* Qout = ws + WS_Q + (size_t)bc * (K_ * K_);
  #pragma unroll
  for (int r = 0; r < 16; ++r) {      // store un-permuted: row = pi(physical row)
    int m_ = (r & 3) + 8 * (r >> 2) + 4 * h;
    Qout[perm_r(m_) * K_ + n] = acc[r];
  }
  if (l == 0) ((int*)ws)[WS_EACC + bc] = eacc;
}

// ---------------- phase 2: sequential combine of 64 chunk matrices per b ----------------
// lane 2k+half holds Q[k][16*half .. +15] in registers; depth-2 global prefetch.
__global__ __launch_bounds__(64) void combine_kernel(float* __restrict__ ws,
                                                     float* __restrict__ out) {
  int l = threadIdx.x;
  int b = blockIdx.x;
  int half = l & 1;
  const ushort* Ew = (const ushort*)(ws + WS_E);
  float alpha = 0.0f;
  if (l < 32) alpha = ws[WS_PI + l] * bf2f(Ew[(size_t)(b * K_ + l) * T_]);
  int escale = 0;
  const int* eaccs = ((const int*)ws) + WS_EACC + b * C_;
  const float4* Qb = (const float4*)(ws + WS_Q + (size_t)b * (C_ * K_ * K_));
  float4 buf[2][4];
  #pragma unroll
  for (int i = 0; i < 4; ++i) buf[0][i] = Qb[0 * 256 + l * 4 + i];
  #pragma unroll
  for (int i = 0; i < 4; ++i) buf[1][i] = Qb[1 * 256 + l * 4 + i];
  for (int c = 0; c < C_; ++c) {
    int pb = c & 1;
    float s = 0.0f;
    #pragma unroll
    for (int i = 0; i < 16; ++i) {     // alpha'[k] = sum_j alpha[j] * Q[k][j]
      float aj = __shfl(alpha, 16 * half + i);
      s = fmaf(aj, ((const float*)&buf[pb][0])[i], s);
    }
    if (c + 2 < C_) {                  // depth-2 prefetch into the buffer just consumed
      #pragma unroll
      for (int i = 0; i < 4; ++i) buf[pb][i] = Qb[(c + 2) * 256 + l * 4 + i];
    }
    s += __shfl_xor(s, 1);             // combine j-halves: lanes 2k,2k+1 hold alpha'[k]
    float mm = s;
    #pragma unroll
    for (int mk = 2; mk <= 32; mk <<= 1) mm = fmaxf(mm, __shfl_xor(mm, mk));
    int ex;
    frexpf(mm, &ex);
    s = ldexpf(s, -ex);
    escale += ex + eaccs[c];
    alpha = __shfl(s, (l & 31) * 2);   // lane j <- alpha'[j]
  }
  if (l < 32) {
    float ssum = alpha;
    #pragma unroll
    for (int mk = 16; mk; mk >>= 1) ssum += __shfl_xor(ssum, mk);
    if (l == 0) {
      float res = logf(ssum) + (float)escale * 0.69314718055994531f + ws[WS_MSUM + b];
      atomicAdd(out, res);
    }
  }
}

extern "C" void kernel_launch(void* const* d_in, const int* in_sizes, int n_in,
                              void* d_out, int out_size, void* d_ws, size_t ws_size,
                              hipStream_t stream) {
  (void)in_sizes; (void)n_in; (void)out_size; (void)ws_size;
  const float* X      = (const float*)d_in[0];
  const float* priors = (const float*)d_in[1];
  const float* trans  = (const float*)d_in[2];
  const float* mu     = (const float*)d_in[3];
  const float* lv     = (const float*)d_in[4];
  float* ws  = (float*)d_ws;
  float* out = (float*)d_out;
  hipMemsetAsync(out, 0, sizeof(float), stream);
  hipMemsetAsync(ws + WS_MSUM, 0, B_ * sizeof(float), stream);
  prep_kernel<<<1, 1024, 0, stream>>>(priors, trans, mu, lv, ws);
  emis_kernel<<<2048, 256, 0, stream>>>(X, ws);
  chunk_kernel<<<B_ * C_, 64, 0, stream>>>(ws);
  combine_kernel<<<B_, 64, 0, stream>>>(ws, out);
}

// Round 4
// 288.046 us; speedup vs baseline: 1.1583x; 1.1583x over previous
//
#include <hip/hip_runtime.h>
#include <stdint.h>

#define B_ 64
#define T_ 4096
#define D_ 90
#define K_ 32
#define C_ 64   // number of T-chunks (chunk length = 64)

typedef float f32x16 __attribute__((ext_vector_type(16)));
typedef __bf16 bf16x8 __attribute__((ext_vector_type(8)));

// ---- workspace layout (float offsets). total ~8405120 floats = 33.6 MB ----
#define WS_A     0          // 1024 : softmax(transition) rows, A[j*32+k]
#define WS_PI    1024       // 32   : softmax(priors)
#define WS_C0    1056       // 32   : per-state emission constant
#define WS_EACC  1152       // 4096 ints : per-(b,chunk) renorm exponent
#define WS_WF    5248       // 6144 bf16 : MFMA B-fragments of emission weights
#define WS_E     8320       // 8388608 bf16 : E^T[b][k][t] = exp(em - m_t)
#define WS_Q     4202624    // 4194304 : Q[b][c][k_new][j_old]
#define WS_MS    8396928    // 8192 : per-wave msum slots (NO atomics — see R3 post-mortem:
                            // contended device-scope atomicAdd serialized at ~12 ns/op and
                            // zombie-waved the whole kernel)

// block-swap involution: swap 4-7<->8-11 and 20-23<->24-27
__device__ __forceinline__ int perm_r(int r) {
  int t2 = (r >> 2) & 3;
  return r + ((t2 == 1) ? 4 : (t2 == 2) ? -4 : 0);
}
// pack two f32 -> bf16x2 dword (truncation; used in chunk recursion)
__device__ __forceinline__ uint32_t pk2(float hi, float lo) {
  return (__float_as_uint(hi) & 0xFFFF0000u) | (__float_as_uint(lo) >> 16);
}
// pack two f32 -> bf16x2 dword with round-to-nearest (emission path)
__device__ __forceinline__ uint32_t rnd_pk(float hi, float lo) {
  uint32_t uh = __float_as_uint(hi) + 0x8000u;
  uint32_t ul = __float_as_uint(lo) + 0x8000u;
  return (uh & 0xFFFF0000u) | (ul >> 16);
}
__device__ __forceinline__ float bf2f(ushort u) {
  return __uint_as_float(((uint32_t)u) << 16);
}
__device__ __forceinline__ bf16x8 mkbf(uint32_t a, uint32_t b, uint32_t c, uint32_t d) {
  union { uint32_t u[4]; bf16x8 v; } x;
  x.u[0] = a; x.u[1] = b; x.u[2] = c; x.u[3] = d;
  return x.v;
}

// ---------------- prep: softmaxes + emission weight fragments ----------------
__global__ __launch_bounds__(1024) void prep_kernel(
    const float* __restrict__ priors, const float* __restrict__ trans,
    const float* __restrict__ mu, const float* __restrict__ lv,
    float* __restrict__ ws) {
  int tid = threadIdx.x;
  {  // transition row softmax: tid = j*32+k, 32-lane groups are rows
    float v = trans[tid];
    float m = v;
    #pragma unroll
    for (int mk = 16; mk; mk >>= 1) m = fmaxf(m, __shfl_xor(m, mk));
    float e = expf(v - m);
    float s = e;
    #pragma unroll
    for (int mk = 16; mk; mk >>= 1) s += __shfl_xor(s, mk);
    ws[WS_A + tid] = e / s;
  }
  if (tid < 32) {  // prior softmax
    float v = priors[tid];
    float m = v;
    #pragma unroll
    for (int mk = 16; mk; mk >>= 1) m = fmaxf(m, __shfl_xor(m, mk));
    float e = expf(v - m);
    float s = e;
    #pragma unroll
    for (int mk = 16; mk; mk >>= 1) s += __shfl_xor(s, mk);
    ws[WS_PI + tid] = e / s;
  }
  // MFMA B-operand weight fragments, bf16, layout [c][mat][lane][j]
  // element = W[d = 16c + 8(lane>>5) + j][k = lane&31]; mat0 = -0.5*iv (x^2), mat1 = mu*iv (x)
  for (int i = tid; i < 6144; i += 1024) {
    int j = i & 7, l = (i >> 3) & 63, cm = i >> 9;
    int c = cm >> 1, mat = cm & 1;
    int h = l >> 5, nn = l & 31;
    int d = 16 * c + 8 * h + j;
    float v = 0.0f;
    if (d < D_) {
      float ivd = expf(-lv[nn * D_ + d]);
      v = (mat == 0) ? -0.5f * ivd : mu[nn * D_ + d] * ivd;
    }
    ((ushort*)(ws + WS_WF))[i] = (ushort)((__float_as_uint(v) + 0x8000u) >> 16);
  }
  if (tid < 32) {  // c0[k] = -0.5*(sum mu^2*iv + sum lv + D*log(2pi))
    float s = 0.0f;
    for (int d = 0; d < D_; ++d) {
      float l  = lv[tid * D_ + d];
      float iv = expf(-l);
      float m_ = mu[tid * D_ + d];
      s += m_ * m_ * iv + l;
    }
    ws[WS_C0 + tid] = -0.5f * (s + (float)D_ * 1.8378770664093453f);
  }
}

// ---------------- emission via MFMA: E^T[b][k][t] = exp(em - m_t) (bf16) ----------------
// LDS-staged X (coalesced float4), then per-wave 32-t tile, 12 mfma_32x32x16_bf16.
// Per-wave msum goes to a PRIVATE slot (plain store) — no contended atomics.
__global__ __launch_bounds__(256) void emis_kernel(const float* __restrict__ X,
                                                   float* __restrict__ ws) {
  __shared__ float xs[4 * 2888];     // 4 wave-regions of 32 rows x 90 (+8 pad)
  int tid = threadIdx.x;
  int l = tid & 63;
  int w = tid >> 6;
  int n = l & 31, h = l >> 5;
  int tB = blockIdx.x << 7;          // block covers 128 contiguous rows
  // stage: 2880 float4, fully coalesced; LDS regions padded per 32-row group
  const float4* Xg = (const float4*)(X + (size_t)tB * D_);
  #pragma unroll
  for (int it = 0; it < 12; ++it) {
    int i = tid + (it << 8);
    if (i < 2880) {
      int g = i / 720;               // 32-row group
      ((float4*)xs)[g * 722 + (i - g * 720)] = Xg[i];
    }
  }
  const uint4* wfp = (const uint4*)((const ushort*)(ws + WS_WF));
  uint4 wf[12];
  #pragma unroll
  for (int cm = 0; cm < 12; ++cm) wf[cm] = wfp[cm * 64 + l];   // coalesced b128
  float c0 = ws[WS_C0 + n];
  __syncthreads();
  int t0 = tB + (w << 5);
  int b  = t0 >> 12;
  const float* xrow = xs + w * 2888 + n * 90;       // A-row m = n
  f32x16 acc1, acc2;
  #pragma unroll
  for (int r = 0; r < 16; ++r) { acc1[r] = 0.0f; acc2[r] = 0.0f; }
  #pragma unroll
  for (int c = 0; c < 6; ++c) {
    float x[8];
    int s = 16 * c + 8 * h;                          // kk = d = s + j
    const float2* p = (const float2*)(xrow + s);     // 8B-aligned, 2-way bank alias (free)
    #pragma unroll
    for (int r = 0; r < 4; ++r) { float2 v = p[r]; x[2*r] = v.x; x[2*r+1] = v.y; }
    if (c == 5) {                                    // zero padded d >= 90
      #pragma unroll
      for (int j = 0; j < 8; ++j) if (s + j >= D_) x[j] = 0.0f;
    }
    union { uint32_t u[4]; bf16x8 v; } xb, x2b;
    #pragma unroll
    for (int r = 0; r < 4; ++r) {
      xb.u[r]  = rnd_pk(x[2*r+1], x[2*r]);
      x2b.u[r] = rnd_pk(x[2*r+1] * x[2*r+1], x[2*r] * x[2*r]);
    }
    union { uint4 u; bf16x8 v; } w2, w1;
    w2.u = wf[c * 2]; w1.u = wf[c * 2 + 1];
    acc1 = __builtin_amdgcn_mfma_f32_32x32x16_bf16(xb.v,  w1.v, acc1, 0, 0, 0);
    acc2 = __builtin_amdgcn_mfma_f32_32x32x16_bf16(x2b.v, w2.v, acc2, 0, 0, 0);
  }
  // C/D: col k = n, row t = (r&3) + 8*(r>>2) + 4*h
  float em[16], mrow[16];
  #pragma unroll
  for (int r = 0; r < 16; ++r) {
    float v = acc1[r] + acc2[r] + c0;
    em[r] = v;
    float m = v;
    #pragma unroll
    for (int mk = 1; mk <= 16; mk <<= 1) m = fmaxf(m, __shfl_xor(m, mk));  // max over k
    mrow[r] = m;
  }
  ushort* Ew = (ushort*)(ws + WS_E);
  size_t ebase = (size_t)(b * K_ + n) * T_ + (t0 & (T_ - 1));
  #pragma unroll
  for (int q = 0; q < 4; ++q) {  // regs 4q..4q+3 are consecutive t's: pack 4 bf16 -> 8B store
    float e0 = exp2f((em[4*q]   - mrow[4*q])   * 1.44269504088896f);
    float e1 = exp2f((em[4*q+1] - mrow[4*q+1]) * 1.44269504088896f);
    float e2 = exp2f((em[4*q+2] - mrow[4*q+2]) * 1.44269504088896f);
    float e3 = exp2f((em[4*q+3] - mrow[4*q+3]) * 1.44269504088896f);
    uint2 d;
    d.x = rnd_pk(e1, e0);
    d.y = rnd_pk(e3, e2);
    *(uint2*)(Ew + ebase + 8 * q + 4 * h) = d;
  }
  float msum = 0.0f;
  #pragma unroll
  for (int r = 0; r < 16; ++r) msum += mrow[r];
  msum += __shfl_xor(msum, 32);                      // both halves' 16 rows
  if (l == 0) ws[WS_MS + (t0 >> 5)] = msum;          // private slot, plain store
}

// ---------------- phase 1: per-(b,chunk) transfer matrix via MFMA ----------------
// E loads vectorized: one uint4 (8 steps) per lane per group, prefetched a group ahead.
__global__ __launch_bounds__(64) void chunk_kernel(float* __restrict__ ws) {
  int l = threadIdx.x;
  int h = l >> 5, n = l & 31;
  int bc = blockIdx.x;
  int b = bc >> 6, c = bc & 63;
  int col = perm_r(n);                // logical output-state of this lane's A column
  const float* A = ws + WS_A;
  float astat[16];                    // A[s][col] for s = 8h+j and 16+8h+j
  #pragma unroll
  for (int j = 0; j < 8; ++j) {
    astat[j]     = A[(8 * h + j) * K_ + col];
    astat[8 + j] = A[(16 + 8 * h + j) * K_ + col];
  }
  uint32_t q[8];                      // Q fragments (bf16x2 dwords), init = I
  #pragma unroll
  for (int r = 0; r < 4; ++r) {
    int s0 = 8 * h + 2 * r;
    uint32_t lo = (s0 == n)     ? 0x3F80u : 0u;
    uint32_t hi = (s0 + 1 == n) ? 0x3F80u : 0u;
    q[r] = lo | (hi << 16);
    int s2 = s0 + 16;
    lo = (s2 == n)     ? 0x3F80u : 0u;
    hi = (s2 + 1 == n) ? 0x3F80u : 0u;
    q[4 + r] = lo | (hi << 16);
  }
  const ushort* Eb = (const ushort*)(ws + WS_E) + (size_t)(b * K_ + col) * T_ + c * 64;
  int eacc = 0;
  f32x16 acc;
  #pragma unroll
  for (int r = 0; r < 16; ++r) acc[r] = 0.0f;

  auto step = [&](float e0) {
    uint32_t au[8];
    #pragma unroll
    for (int r = 0; r < 4; ++r) {     // A-frag = astat * E[col], truncated to bf16
      au[r]     = pk2(astat[2 * r + 1] * e0, astat[2 * r] * e0);
      au[4 + r] = pk2(astat[8 + 2 * r + 1] * e0, astat[8 + 2 * r] * e0);
    }
    bf16x8 alo = mkbf(au[0], au[1], au[2], au[3]);
    bf16x8 ahi = mkbf(au[4], au[5], au[6], au[7]);
    bf16x8 qlo = mkbf(q[0], q[1], q[2], q[3]);
    bf16x8 qhi = mkbf(q[4], q[5], q[6], q[7]);
    f32x16 z;
    #pragma unroll
    for (int r = 0; r < 16; ++r) z[r] = 0.0f;
    acc = __builtin_amdgcn_mfma_f32_32x32x16_bf16(alo, qlo, z, 0, 0, 0);
    acc = __builtin_amdgcn_mfma_f32_32x32x16_bf16(ahi, qhi, acc, 0, 0, 0);
    #pragma unroll
    for (int r = 0; r < 4; ++r) {     // D regs -> next B-frag, in-lane repack only
      q[r]     = pk2(acc[2 * r + 1], acc[2 * r]);
      q[4 + r] = pk2(acc[8 + 2 * r + 1], acc[8 + 2 * r]);
    }
  };
  auto renorm = [&]() {               // exact power-of-2 renormalization
    float m = acc[0];
    #pragma unroll
    for (int r = 1; r < 16; ++r) m = fmaxf(m, acc[r]);
    #pragma unroll
    for (int mk = 1; mk <= 32; mk <<= 1) m = fmaxf(m, __shfl_xor(m, mk));
    int ex;
    frexpf(m, &ex);
    float sc = ldexpf(1.0f, -ex);
    eacc += ex;
    #pragma unroll
    for (int r = 0; r < 16; ++r) acc[r] *= sc;
    #pragma unroll
    for (int r = 0; r < 4; ++r) {     // re-pack q from renormalized acc
      q[r]     = pk2(acc[2 * r + 1], acc[2 * r]);
      q[4 + r] = pk2(acc[8 + 2 * r + 1], acc[8 + 2 * r]);
    }
  };

  uint4 ev = *(const uint4*)(Eb);     // group 0 (8 steps of E, 16B)
  int gstart = 0;
  if (c == 0) {                       // t=0 is the prior step: skip it
    uint4 evn = *(const uint4*)(Eb + 8);
    #pragma unroll
    for (int j = 1; j < 8; ++j) {
      uint32_t u = ((const uint32_t*)&ev)[j >> 1];
      step(bf2f((j & 1) ? (ushort)(u >> 16) : (ushort)(u & 0xFFFF)));
    }
    renorm();
    ev = evn;
    gstart = 1;
  }
  for (int g = gstart; g < 8; ++g) {
    uint4 evn;
    if (g < 7) evn = *(const uint4*)(Eb + 8 * (g + 1));   // prefetch next group
    #pragma unroll
    for (int j = 0; j < 8; ++j) {
      uint32_t u = ((const uint32_t*)&ev)[j >> 1];
      step(bf2f((j & 1) ? (ushort)(u >> 16) : (ushort)(u & 0xFFFF)));
    }
    renorm();
    ev = evn;
  }
  float* Qout = ws + WS_Q + (size_t)bc * (K_ * K_);
  #pragma unroll
  for (int r = 0; r < 16; ++r) {      // store un-permuted: row = pi(physical row)
    int m_ = (r & 3) + 8 * (r >> 2) + 4 * h;
    Qout[perm_r(m_) * K_ + n] = acc[r];
  }
  if (l == 0) ((int*)ws)[WS_EACC + bc] = eacc;
}

// ---------------- phase 2: sequential combine of 64 chunk matrices per b ----------------
// lane 2k+half holds Q[k][16*half .. +15] in registers; depth-2 global prefetch.
// Also sums this b's 128 per-wave msum slots (replaces the old contended atomic).
__global__ __launch_bounds__(64) void combine_kernel(float* __restrict__ ws,
                                                     float* __restrict__ out) {
  int l = threadIdx.x;
  int b = blockIdx.x;
  int half = l & 1;
  const ushort* Ew = (const ushort*)(ws + WS_E);
  float alpha = 0.0f;
  if (l < 32) alpha = ws[WS_PI + l] * bf2f(Ew[(size_t)(b * K_ + l) * T_]);
  // msum reduction: 128 slots for this b
  float msm = ws[WS_MS + b * 128 + l] + ws[WS_MS + b * 128 + 64 + l];
  #pragma unroll
  for (int mk = 32; mk; mk >>= 1) msm += __shfl_xor(msm, mk);
  int escale = 0;
  const int* eaccs = ((const int*)ws) + WS_EACC + b * C_;
  const float4* Qb = (const float4*)(ws + WS_Q + (size_t)b * (C_ * K_ * K_));
  float4 buf[2][4];
  #pragma unroll
  for (int i = 0; i < 4; ++i) buf[0][i] = Qb[0 * 256 + l * 4 + i];
  #pragma unroll
  for (int i = 0; i < 4; ++i) buf[1][i] = Qb[1 * 256 + l * 4 + i];
  for (int c = 0; c < C_; ++c) {
    int pb = c & 1;
    float s = 0.0f;
    #pragma unroll
    for (int i = 0; i < 16; ++i) {     // alpha'[k] = sum_j alpha[j] * Q[k][j]
      float aj = __shfl(alpha, 16 * half + i);
      s = fmaf(aj, ((const float*)&buf[pb][0])[i], s);
    }
    if (c + 2 < C_) {                  // depth-2 prefetch into the buffer just consumed
      #pragma unroll
      for (int i = 0; i < 4; ++i) buf[pb][i] = Qb[(c + 2) * 256 + l * 4 + i];
    }
    s += __shfl_xor(s, 1);             // combine j-halves: lanes 2k,2k+1 hold alpha'[k]
    float mm = s;
    #pragma unroll
    for (int mk = 2; mk <= 32; mk <<= 1) mm = fmaxf(mm, __shfl_xor(mm, mk));
    int ex;
    frexpf(mm, &ex);
    s = ldexpf(s, -ex);
    escale += ex + eaccs[c];
    alpha = __shfl(s, (l & 31) * 2);   // lane j <- alpha'[j]
  }
  if (l < 32) {
    float ssum = alpha;
    #pragma unroll
    for (int mk = 16; mk; mk >>= 1) ssum += __shfl_xor(ssum, mk);
    if (l == 0) {
      float res = logf(ssum) + (float)escale * 0.69314718055994531f + msm;
      atomicAdd(out, res);
    }
  }
}

extern "C" void kernel_launch(void* const* d_in, const int* in_sizes, int n_in,
                              void* d_out, int out_size, void* d_ws, size_t ws_size,
                              hipStream_t stream) {
  (void)in_sizes; (void)n_in; (void)out_size; (void)ws_size;
  const float* X      = (const float*)d_in[0];
  const float* priors = (const float*)d_in[1];
  const float* trans  = (const float*)d_in[2];
  const float* mu     = (const float*)d_in[3];
  const float* lv     = (const float*)d_in[4];
  float* ws  = (float*)d_ws;
  float* out = (float*)d_out;
  hipMemsetAsync(out, 0, sizeof(float), stream);
  prep_kernel<<<1, 1024, 0, stream>>>(priors, trans, mu, lv, ws);
  emis_kernel<<<2048, 256, 0, stream>>>(X, ws);
  chunk_kernel<<<B_ * C_, 64, 0, stream>>>(ws);
  combine_kernel<<<B_, 64, 0, stream>>>(ws, out);
}

// Round 5
// 243.717 us; speedup vs baseline: 1.3690x; 1.1819x over previous
//
#include <hip/hip_runtime.h>
#include <stdint.h>

#define B_ 64
#define T_ 4096
#define D_ 90
#define K_ 32
#define CH_ 256  // chunk length (R5: 64 -> 256 to cut combine's serial iterations)
#define F_  16   // number of T-chunks = T_/CH_

typedef float f32x16 __attribute__((ext_vector_type(16)));
typedef __bf16 bf16x8 __attribute__((ext_vector_type(8)));

// ---- workspace layout (float offsets). total ~5259392 floats = 21 MB ----
#define WS_A     0          // 1024 : softmax(transition) rows, A[j*32+k]
#define WS_PI    1024       // 32   : softmax(priors)
#define WS_C0    1056       // 32   : per-state emission constant
#define WS_EACC  1152       // 1024 ints : per-(b,chunk) renorm exponent
#define WS_WF    5248       // 6144 bf16 : MFMA B-fragments of emission weights
#define WS_E     8320       // 8388608 bf16 : E^T[b][k][t] = exp(em - m_t)
#define WS_Q     4202624    // 1048576 : Q[b][c][k_new][j_old]
#define WS_MS    5251200    // 8192 : per-wave msum slots (NO atomics — R3: contended
                            // device-scope atomicAdd serialized at ~12 ns/op)

// block-swap involution: swap 4-7<->8-11 and 20-23<->24-27
__device__ __forceinline__ int perm_r(int r) {
  int t2 = (r >> 2) & 3;
  return r + ((t2 == 1) ? 4 : (t2 == 2) ? -4 : 0);
}
// pack two f32 -> bf16x2 dword (truncation; used in chunk recursion)
__device__ __forceinline__ uint32_t pk2(float hi, float lo) {
  return (__float_as_uint(hi) & 0xFFFF0000u) | (__float_as_uint(lo) >> 16);
}
// pack two f32 -> bf16x2 dword with round-to-nearest (emission path)
__device__ __forceinline__ uint32_t rnd_pk(float hi, float lo) {
  uint32_t uh = __float_as_uint(hi) + 0x8000u;
  uint32_t ul = __float_as_uint(lo) + 0x8000u;
  return (uh & 0xFFFF0000u) | (ul >> 16);
}
__device__ __forceinline__ float bf2f(ushort u) {
  return __uint_as_float(((uint32_t)u) << 16);
}
__device__ __forceinline__ bf16x8 mkbf(uint32_t a, uint32_t b, uint32_t c, uint32_t d) {
  union { uint32_t u[4]; bf16x8 v; } x;
  x.u[0] = a; x.u[1] = b; x.u[2] = c; x.u[3] = d;
  return x.v;
}

// ---------------- prep: softmaxes + emission weight fragments ----------------
__global__ __launch_bounds__(1024) void prep_kernel(
    const float* __restrict__ priors, const float* __restrict__ trans,
    const float* __restrict__ mu, const float* __restrict__ lv,
    float* __restrict__ ws) {
  int tid = threadIdx.x;
  {  // transition row softmax: tid = j*32+k, 32-lane groups are rows
    float v = trans[tid];
    float m = v;
    #pragma unroll
    for (int mk = 16; mk; mk >>= 1) m = fmaxf(m, __shfl_xor(m, mk));
    float e = expf(v - m);
    float s = e;
    #pragma unroll
    for (int mk = 16; mk; mk >>= 1) s += __shfl_xor(s, mk);
    ws[WS_A + tid] = e / s;
  }
  if (tid < 32) {  // prior softmax
    float v = priors[tid];
    float m = v;
    #pragma unroll
    for (int mk = 16; mk; mk >>= 1) m = fmaxf(m, __shfl_xor(m, mk));
    float e = expf(v - m);
    float s = e;
    #pragma unroll
    for (int mk = 16; mk; mk >>= 1) s += __shfl_xor(s, mk);
    ws[WS_PI + tid] = e / s;
  }
  // MFMA B-operand weight fragments, bf16, layout [c][mat][lane][j]
  // element = W[d = 16c + 8(lane>>5) + j][k = lane&31]; mat0 = -0.5*iv (x^2), mat1 = mu*iv (x)
  for (int i = tid; i < 6144; i += 1024) {
    int j = i & 7, l = (i >> 3) & 63, cm = i >> 9;
    int c = cm >> 1, mat = cm & 1;
    int h = l >> 5, nn = l & 31;
    int d = 16 * c + 8 * h + j;
    float v = 0.0f;
    if (d < D_) {
      float ivd = expf(-lv[nn * D_ + d]);
      v = (mat == 0) ? -0.5f * ivd : mu[nn * D_ + d] * ivd;
    }
    ((ushort*)(ws + WS_WF))[i] = (ushort)((__float_as_uint(v) + 0x8000u) >> 16);
  }
  if (tid < 32) {  // c0[k] = -0.5*(sum mu^2*iv + sum lv + D*log(2pi))
    float s = 0.0f;
    for (int d = 0; d < D_; ++d) {
      float l  = lv[tid * D_ + d];
      float iv = expf(-l);
      float m_ = mu[tid * D_ + d];
      s += m_ * m_ * iv + l;
    }
    ws[WS_C0 + tid] = -0.5f * (s + (float)D_ * 1.8378770664093453f);
  }
}

// ---------------- emission via MFMA: E^T[b][k][t] = exp(em - m_t) (bf16) ----------------
// LDS-staged X (coalesced float4), then per-wave 32-t tile, 12 mfma_32x32x16_bf16.
// Per-wave msum goes to a PRIVATE slot (plain store) — no contended atomics.
__global__ __launch_bounds__(256) void emis_kernel(const float* __restrict__ X,
                                                   float* __restrict__ ws) {
  __shared__ float xs[4 * 2888];     // 4 wave-regions of 32 rows x 90 (+8 pad)
  int tid = threadIdx.x;
  int l = tid & 63;
  int w = tid >> 6;
  int n = l & 31, h = l >> 5;
  int tB = blockIdx.x << 7;          // block covers 128 contiguous rows
  // stage: 2880 float4, fully coalesced; LDS regions padded per 32-row group
  const float4* Xg = (const float4*)(X + (size_t)tB * D_);
  #pragma unroll
  for (int it = 0; it < 12; ++it) {
    int i = tid + (it << 8);
    if (i < 2880) {
      int g = i / 720;               // 32-row group
      ((float4*)xs)[g * 722 + (i - g * 720)] = Xg[i];
    }
  }
  const uint4* wfp = (const uint4*)((const ushort*)(ws + WS_WF));
  uint4 wf[12];
  #pragma unroll
  for (int cm = 0; cm < 12; ++cm) wf[cm] = wfp[cm * 64 + l];   // coalesced b128
  float c0 = ws[WS_C0 + n];
  __syncthreads();
  int t0 = tB + (w << 5);
  int b  = t0 >> 12;
  const float* xrow = xs + w * 2888 + n * 90;       // A-row m = n
  f32x16 acc1, acc2;
  #pragma unroll
  for (int r = 0; r < 16; ++r) { acc1[r] = 0.0f; acc2[r] = 0.0f; }
  #pragma unroll
  for (int c = 0; c < 6; ++c) {
    float x[8];
    int s = 16 * c + 8 * h;                          // kk = d = s + j
    const float2* p = (const float2*)(xrow + s);     // 8B-aligned, 2-way bank alias (free)
    #pragma unroll
    for (int r = 0; r < 4; ++r) { float2 v = p[r]; x[2*r] = v.x; x[2*r+1] = v.y; }
    if (c == 5) {                                    // zero padded d >= 90
      #pragma unroll
      for (int j = 0; j < 8; ++j) if (s + j >= D_) x[j] = 0.0f;
    }
    union { uint32_t u[4]; bf16x8 v; } xb, x2b;
    #pragma unroll
    for (int r = 0; r < 4; ++r) {
      xb.u[r]  = rnd_pk(x[2*r+1], x[2*r]);
      x2b.u[r] = rnd_pk(x[2*r+1] * x[2*r+1], x[2*r] * x[2*r]);
    }
    union { uint4 u; bf16x8 v; } w2, w1;
    w2.u = wf[c * 2]; w1.u = wf[c * 2 + 1];
    acc1 = __builtin_amdgcn_mfma_f32_32x32x16_bf16(xb.v,  w1.v, acc1, 0, 0, 0);
    acc2 = __builtin_amdgcn_mfma_f32_32x32x16_bf16(x2b.v, w2.v, acc2, 0, 0, 0);
  }
  // C/D: col k = n, row t = (r&3) + 8*(r>>2) + 4*h
  float em[16], mrow[16];
  #pragma unroll
  for (int r = 0; r < 16; ++r) {
    float v = acc1[r] + acc2[r] + c0;
    em[r] = v;
    float m = v;
    #pragma unroll
    for (int mk = 1; mk <= 16; mk <<= 1) m = fmaxf(m, __shfl_xor(m, mk));  // max over k
    mrow[r] = m;
  }
  ushort* Ew = (ushort*)(ws + WS_E);
  size_t ebase = (size_t)(b * K_ + n) * T_ + (t0 & (T_ - 1));
  #pragma unroll
  for (int q = 0; q < 4; ++q) {  // regs 4q..4q+3 are consecutive t's: pack 4 bf16 -> 8B store
    float e0 = exp2f((em[4*q]   - mrow[4*q])   * 1.44269504088896f);
    float e1 = exp2f((em[4*q+1] - mrow[4*q+1]) * 1.44269504088896f);
    float e2 = exp2f((em[4*q+2] - mrow[4*q+2]) * 1.44269504088896f);
    float e3 = exp2f((em[4*q+3] - mrow[4*q+3]) * 1.44269504088896f);
    uint2 d;
    d.x = rnd_pk(e1, e0);
    d.y = rnd_pk(e3, e2);
    *(uint2*)(Ew + ebase + 8 * q + 4 * h) = d;
  }
  float msum = 0.0f;
  #pragma unroll
  for (int r = 0; r < 16; ++r) msum += mrow[r];
  msum += __shfl_xor(msum, 32);                      // both halves' 16 rows
  if (l == 0) ws[WS_MS + (t0 >> 5)] = msum;          // private slot, plain store
}

// ---------------- phase 1: per-(b,chunk) transfer matrix via MFMA ----------------
// 256 steps per chunk; E loads vectorized (uint4 = 8 steps), prefetched a group ahead.
__global__ __launch_bounds__(64) void chunk_kernel(float* __restrict__ ws) {
  int l = threadIdx.x;
  int h = l >> 5, n = l & 31;
  int bc = blockIdx.x;               // 0..1023
  int b = bc >> 4, c = bc & (F_ - 1);
  int col = perm_r(n);                // logical output-state of this lane's A column
  const float* A = ws + WS_A;
  float astat[16];                    // A[s][col] for s = 8h+j and 16+8h+j
  #pragma unroll
  for (int j = 0; j < 8; ++j) {
    astat[j]     = A[(8 * h + j) * K_ + col];
    astat[8 + j] = A[(16 + 8 * h + j) * K_ + col];
  }
  uint32_t q[8];                      // Q fragments (bf16x2 dwords), init = I
  #pragma unroll
  for (int r = 0; r < 4; ++r) {
    int s0 = 8 * h + 2 * r;
    uint32_t lo = (s0 == n)     ? 0x3F80u : 0u;
    uint32_t hi = (s0 + 1 == n) ? 0x3F80u : 0u;
    q[r] = lo | (hi << 16);
    int s2 = s0 + 16;
    lo = (s2 == n)     ? 0x3F80u : 0u;
    hi = (s2 + 1 == n) ? 0x3F80u : 0u;
    q[4 + r] = lo | (hi << 16);
  }
  const ushort* Eb = (const ushort*)(ws + WS_E) + (size_t)(b * K_ + col) * T_ + c * CH_;
  int eacc = 0;
  f32x16 acc;
  #pragma unroll
  for (int r = 0; r < 16; ++r) acc[r] = 0.0f;

  auto step = [&](float e0) {
    uint32_t au[8];
    #pragma unroll
    for (int r = 0; r < 4; ++r) {     // A-frag = astat * E[col], truncated to bf16
      au[r]     = pk2(astat[2 * r + 1] * e0, astat[2 * r] * e0);
      au[4 + r] = pk2(astat[8 + 2 * r + 1] * e0, astat[8 + 2 * r] * e0);
    }
    bf16x8 alo = mkbf(au[0], au[1], au[2], au[3]);
    bf16x8 ahi = mkbf(au[4], au[5], au[6], au[7]);
    bf16x8 qlo = mkbf(q[0], q[1], q[2], q[3]);
    bf16x8 qhi = mkbf(q[4], q[5], q[6], q[7]);
    f32x16 z;
    #pragma unroll
    for (int r = 0; r < 16; ++r) z[r] = 0.0f;
    acc = __builtin_amdgcn_mfma_f32_32x32x16_bf16(alo, qlo, z, 0, 0, 0);
    acc = __builtin_amdgcn_mfma_f32_32x32x16_bf16(ahi, qhi, acc, 0, 0, 0);
    #pragma unroll
    for (int r = 0; r < 4; ++r) {     // D regs -> next B-frag, in-lane repack only
      q[r]     = pk2(acc[2 * r + 1], acc[2 * r]);
      q[4 + r] = pk2(acc[8 + 2 * r + 1], acc[8 + 2 * r]);
    }
  };
  auto renorm = [&]() {               // exact power-of-2 renormalization
    float m = acc[0];
    #pragma unroll
    for (int r = 1; r < 16; ++r) m = fmaxf(m, acc[r]);
    #pragma unroll
    for (int mk = 1; mk <= 32; mk <<= 1) m = fmaxf(m, __shfl_xor(m, mk));
    int ex;
    frexpf(m, &ex);
    float sc = ldexpf(1.0f, -ex);
    eacc += ex;
    #pragma unroll
    for (int r = 0; r < 16; ++r) acc[r] *= sc;
    #pragma unroll
    for (int r = 0; r < 4; ++r) {     // re-pack q from renormalized acc
      q[r]     = pk2(acc[2 * r + 1], acc[2 * r]);
      q[4 + r] = pk2(acc[8 + 2 * r + 1], acc[8 + 2 * r]);
    }
  };

  uint4 ev = *(const uint4*)(Eb);     // group 0 (8 steps of E, 16B)
  int gstart = 0;
  if (c == 0) {                       // t=0 is the prior step: skip it
    uint4 evn = *(const uint4*)(Eb + 8);
    #pragma unroll
    for (int j = 1; j < 8; ++j) {
      uint32_t u = ((const uint32_t*)&ev)[j >> 1];
      step(bf2f((j & 1) ? (ushort)(u >> 16) : (ushort)(u & 0xFFFF)));
    }
    renorm();
    ev = evn;
    gstart = 1;
  }
  for (int g = gstart; g < CH_ / 8; ++g) {
    uint4 evn;
    if (g < CH_ / 8 - 1) evn = *(const uint4*)(Eb + 8 * (g + 1));  // prefetch next group
    #pragma unroll
    for (int j = 0; j < 8; ++j) {
      uint32_t u = ((const uint32_t*)&ev)[j >> 1];
      step(bf2f((j & 1) ? (ushort)(u >> 16) : (ushort)(u & 0xFFFF)));
    }
    renorm();
    ev = evn;
  }
  float* Qout = ws + WS_Q + (size_t)bc * (K_ * K_);
  #pragma unroll
  for (int r = 0; r < 16; ++r) {      // store un-permuted: row = pi(physical row)
    int m_ = (r & 3) + 8 * (r >> 2) + 4 * h;
    Qout[perm_r(m_) * K_ + n] = acc[r];
  }
  if (l == 0) ((int*)ws)[WS_EACC + bc] = eacc;
}

// ---------------- phase 2: sequential combine of 16 chunk matrices per b ----------------
// lane 2k+half holds Q[k][16*half..+15] in registers; depth-4 prefetch ring;
// renorm every 4 iterations (growth <= 32^4 per window — fp32-safe).
__global__ __launch_bounds__(64) void combine_kernel(float* __restrict__ ws,
                                                     float* __restrict__ out) {
  int l = threadIdx.x;
  int b = blockIdx.x;
  int half = l & 1;
  const ushort* Ew = (const ushort*)(ws + WS_E);
  float alpha = 0.0f;
  if (l < 32) alpha = ws[WS_PI + l] * bf2f(Ew[(size_t)(b * K_ + l) * T_]);
  // msum reduction: 128 slots for this b
  float msm = ws[WS_MS + b * 128 + l] + ws[WS_MS + b * 128 + 64 + l];
  #pragma unroll
  for (int mk = 32; mk; mk >>= 1) msm += __shfl_xor(msm, mk);
  int escale = 0;
  const int* eaccs = ((const int*)ws) + WS_EACC + b * F_;
  const float4* Qb = (const float4*)(ws + WS_Q + (size_t)b * (F_ * K_ * K_));
  float4 buf[4][4];
  #pragma unroll
  for (int p = 0; p < 4; ++p)
    #pragma unroll
    for (int i = 0; i < 4; ++i) buf[p][i] = Qb[p * 256 + l * 4 + i];
  for (int c = 0; c < F_; ++c) {
    int pb = c & 3;
    float s0 = 0.0f, s1 = 0.0f;        // split dot chain to halve fma latency
    #pragma unroll
    for (int i = 0; i < 8; ++i) {
      float aj = __shfl(alpha, 16 * half + i);
      s0 = fmaf(aj, ((const float*)&buf[pb][0])[i], s0);
    }
    #pragma unroll
    for (int i = 8; i < 16; ++i) {
      float aj = __shfl(alpha, 16 * half + i);
      s1 = fmaf(aj, ((const float*)&buf[pb][0])[i], s1);
    }
    float s = s0 + s1;
    if (c + 4 < F_) {                  // depth-4 prefetch into the buffer just consumed
      #pragma unroll
      for (int i = 0; i < 4; ++i) buf[pb][i] = Qb[(c + 4) * 256 + l * 4 + i];
    }
    s += __shfl_xor(s, 1);             // combine j-halves: lanes 2k,2k+1 hold alpha'[k]
    if ((c & 3) == 3) {                // renorm every 4 iterations
      float mm = s;
      #pragma unroll
      for (int mk = 2; mk <= 32; mk <<= 1) mm = fmaxf(mm, __shfl_xor(mm, mk));
      int ex;
      frexpf(mm, &ex);
      s = ldexpf(s, -ex);
      escale += ex;
    }
    escale += eaccs[c];
    alpha = __shfl(s, (l & 31) * 2);   // lane j <- alpha'[j]
  }
  if (l < 32) {
    float ssum = alpha;
    #pragma unroll
    for (int mk = 16; mk; mk >>= 1) ssum += __shfl_xor(ssum, mk);
    if (l == 0) {
      float res = logf(ssum) + (float)escale * 0.69314718055994531f + msm;
      atomicAdd(out, res);
    }
  }
}

extern "C" void kernel_launch(void* const* d_in, const int* in_sizes, int n_in,
                              void* d_out, int out_size, void* d_ws, size_t ws_size,
                              hipStream_t stream) {
  (void)in_sizes; (void)n_in; (void)out_size; (void)ws_size;
  const float* X      = (const float*)d_in[0];
  const float* priors = (const float*)d_in[1];
  const float* trans  = (const float*)d_in[2];
  const float* mu     = (const float*)d_in[3];
  const float* lv     = (const float*)d_in[4];
  float* ws  = (float*)d_ws;
  float* out = (float*)d_out;
  hipMemsetAsync(out, 0, sizeof(float), stream);
  prep_kernel<<<1, 1024, 0, stream>>>(priors, trans, mu, lv, ws);
  emis_kernel<<<2048, 256, 0, stream>>>(X, ws);
  chunk_kernel<<<B_ * F_, 64, 0, stream>>>(ws);
  combine_kernel<<<B_, 64, 0, stream>>>(ws, out);
}